// Round 4
// baseline (708.998 us; speedup 1.0000x reference)
//
#include <hip/hip_runtime.h>

// Problem constants (fixed by the reference): B=256, N=2048, D=128, ANCHOR=0
#define B_SZ    256
#define N_NODES 2048
#define D_DIM   128

typedef __attribute__((ext_vector_type(8))) short short8;   // 8 bf16 (MFMA A/B frag)
typedef __attribute__((ext_vector_type(4))) float f32x4;    // MFMA C/D frag

// ---- workspace layout (bytes) ----
#define WS_W1BF    0          // 128*256 bf16 = 65536
#define WS_CNT     65536      // 256 * 4
#define WS_SCRATCH 66560      // 256 blocks * 32768 floats * 4 = 33554432

// RNE fp32->bf16 pack of two floats into one uint (lo = first)
__device__ __forceinline__ unsigned pk2(float x, float y) {
    unsigned a = __float_as_uint(x), b = __float_as_uint(y);
    a += 0x7fffu + ((a >> 16) & 1u);
    b += 0x7fffu + ((b >> 16) & 1u);
    return (a >> 16) | (b & 0xffff0000u);
}

__device__ __forceinline__ short8 pack8(float4 a, float4 b) {
    union { unsigned u[4]; short8 s; } r;
    r.u[0] = pk2(a.x, a.y); r.u[1] = pk2(a.z, a.w);
    r.u[2] = pk2(b.x, b.y); r.u[3] = pk2(b.z, b.w);
    return r.s;
}

__device__ __forceinline__ float bf2f(short s) {
    return __uint_as_float(((unsigned)(unsigned short)s) << 16);
}

// ---- W1 (128x256 fp32, row-major [d][k]) -> bf16 same layout ----
__global__ void k_prep_w1(const float* __restrict__ W1, unsigned* __restrict__ w1bf) {
    int i = blockIdx.x * 256 + threadIdx.x;           // 16384 float2 pairs
    float2 f = ((const float2*)W1)[i];
    w1bf[i] = pk2(f.x, f.y);
}

// ---- histogram of batch_idx over non-anchor rows (for the b2*count term) ----
__global__ void k_hist(const int* __restrict__ bidx, int* __restrict__ count) {
    __shared__ int lh[256];
    int t = threadIdx.x;
    lh[t] = 0;
    __syncthreads();
    int base = blockIdx.x * 1024 + t * 4;
    int4 v = ((const int4*)bidx)[blockIdx.x * 256 + t];
    if (((base + 0) & 2047) != 0) atomicAdd(&lh[v.x], 1);
    if (((base + 1) & 2047) != 0) atomicAdd(&lh[v.y], 1);
    if (((base + 2) & 2047) != 0) atomicAdd(&lh[v.z], 1);
    if (((base + 3) & 2047) != 0) atomicAdd(&lh[v.w], 1);
    __syncthreads();
    if (lh[t]) atomicAdd(&count[t], lh[t]);
}

// ---- main: block b streams batch b's 2048 rows. BARRIER-FREE main loop:
//      each wave owns 16 rows/chunk, loads A global->reg in MFMA layout,
//      computes all 128 cols (B frags from LDS, frag-contiguous = conflict-
//      free), segment-accumulates into a 128KB LDS sacc via ds_add.
//      K=128 (target half folded into per-batch bias tb). ----
__global__ __launch_bounds__(1024) void k_main(
    const float* __restrict__ embs, const float* __restrict__ W1,
    const float* __restrict__ b1, const short* __restrict__ w1bf,
    const int* __restrict__ bidx, float* __restrict__ scratch)
{
    __shared__ float sacc[B_SZ * D_DIM];   // 131072 B (also prologue temp space)
    __shared__ char  bfrag[32768];         // 2048 frags x 16B, frag-contiguous

    int tid = threadIdx.x;
    int b   = blockIdx.x;
    int lane = tid & 63, wid = tid >> 6;   // wid 0..15
    int q = lane >> 4, i15 = lane & 15;

    // ---- stage B fragments (frag-contiguous): f = tacc*256 + kt*64 + q*16 + i15
    {
#pragma unroll
        for (int rep = 0; rep < 2; rep++) {
            int f = tid + rep * 1024;
            int tacc = f >> 8, rem = f & 255;
            int kt = rem >> 6, q2 = (rem >> 4) & 3, i2 = rem & 15;
            int n = (tacc >> 1) * 32 + (tacc & 1) * 16 + i2;
            short8 v = *(const short8*)(w1bf + n * 256 + 128 + kt * 32 + q2 * 8);
            *(short8*)(bfrag + f * 16) = v;
        }
    }

    // ---- prologue temps inside sacc: [0..127]=tgtf [128..255]=tgtb
    //      [256..383]=tb [384..511]=t2
    if (tid < 128) {
        float v = embs[(size_t)(b << 11) * D_DIM + tid];   // anchor row
        sacc[tid] = v;
        unsigned ub = __float_as_uint(v);
        ub += 0x7fffu + ((ub >> 16) & 1u);
        sacc[128 + tid] = __uint_as_float(ub & 0xffff0000u);
    }
    __syncthreads();

    if (tid < 128) {
        // tb[d] = b1[d] + fp32 dot(tgt, W1_target_half[d])
        float s = b1[tid];
        const float4* w = (const float4*)(W1 + tid * 256);
#pragma unroll
        for (int k = 0; k < 32; k++) {
            float4 wv = w[k];
            s += sacc[4 * k + 0] * wv.x + sacc[4 * k + 1] * wv.y
               + sacc[4 * k + 2] * wv.z + sacc[4 * k + 3] * wv.w;
        }
        sacc[256 + tid] = s;
    } else if (tid < 256) {
        // t2[d] = bf16 dot(tgt_bf, W1emb_bf[d]) — same arithmetic as MFMA path
        int d = tid - 128;
        float s = 0.f;
        const short8* wr = (const short8*)(w1bf + d * 256 + 128);
#pragma unroll
        for (int k8 = 0; k8 < 16; k8++) {
            short8 v = wr[k8];
#pragma unroll
            for (int j = 0; j < 8; j++) s += sacc[128 + k8 * 8 + j] * bf2f(v[j]);
        }
        sacc[384 + d] = s;
    }
    __syncthreads();

    // per-thread copies of tb for its 8 (cg,ct) column slots; anchor h
    float tbv[8];
#pragma unroll
    for (int tacc = 0; tacc < 8; tacc++)
        tbv[tacc] = sacc[256 + (tacc >> 1) * 32 + (tacc & 1) * 16 + i15];
    float h_anchor = 0.f;
    int   seg0 = 0;
    if (tid < 128) {
        h_anchor = fmaxf(sacc[384 + tid] + sacc[256 + tid], 0.f);
        seg0 = bidx[b << 11];
    }
    __syncthreads();          // temps consumed

    for (int i = tid; i < B_SZ * D_DIM; i += 1024) sacc[i] = 0.f;
    __syncthreads();          // sacc zeroed, bfrag staged

    // ---- barrier-free main loop: 8 chunks x (16 waves x 16 rows) ----
    const char* bbase = bfrag + (q * 16 + i15) * 16;  // lane-consecutive -> conflict-free
    for (int c = 0; c < 8; c++) {
        int rowb = (b << 11) + c * 256 + wid * 16;
        const float* ap = embs + (size_t)(rowb + i15) * D_DIM + q * 8;

        // A frags: lane (q,i15) holds A[m=i15][k=kt*32+q*8 ..+8]
        short8 a[4];
#pragma unroll
        for (int kt = 0; kt < 4; kt++)
            a[kt] = pack8(*(const float4*)(ap + kt * 32),
                          *(const float4*)(ap + kt * 32 + 4));

        int4 sv = *(const int4*)(bidx + rowb + q * 4);
        int svv[4] = {sv.x, sv.y, sv.z, sv.w};

        f32x4 m[8];
#pragma unroll
        for (int t = 0; t < 8; t++) m[t] = (f32x4){0.f, 0.f, 0.f, 0.f};

#pragma unroll
        for (int tacc = 0; tacc < 8; tacc++) {
#pragma unroll
            for (int kt = 0; kt < 4; kt++) {
                short8 bw = *(const short8*)(bbase + (tacc * 256 + kt * 64) * 16);
                m[tacc] = __builtin_amdgcn_mfma_f32_16x16x32_bf16(a[kt], bw, m[tacc], 0, 0, 0);
            }
        }

        // epilogue: h = relu(m + tb); ds_add into sacc (seg-parity XOR swizzle)
#pragma unroll
        for (int tacc = 0; tacc < 8; tacc++) {
            int col = (tacc >> 1) * 32 + (tacc & 1) * 16 + i15;
#pragma unroll
            for (int j = 0; j < 4; j++) {
                int seg = svv[j];
                atomicAdd(&sacc[seg * D_DIM + (col ^ ((seg & 1) << 4))],
                          fmaxf(m[tacc][j] + tbv[tacc], 0.f));
            }
        }
    }
    __syncthreads();

    // remove the anchor row's contribution (processed uniformly above)
    if (tid < 128)
        atomicAdd(&sacc[seg0 * D_DIM + (tid ^ ((seg0 & 1) << 4))], -h_anchor);
    __syncthreads();

    // flush per-block partials: scratch[b][seg][col] (un-swizzle), coalesced
    float* dst = scratch + (size_t)b * (B_SZ * D_DIM);
    for (int i = tid; i < B_SZ * D_DIM; i += 1024) {
        int seg = i >> 7, col = i & 127;
        dst[i] = sacc[seg * D_DIM + (col ^ ((seg & 1) << 4))];
    }
}

// ---- reduce 256 partials, apply W2 and count*b2 ----
__global__ void k_out(const float* __restrict__ scratch, const float* __restrict__ W2,
                      const float* __restrict__ b2, const int* __restrict__ count,
                      float* __restrict__ out) {
    __shared__ float a[D_DIM];
    int s = blockIdx.x, d = threadIdx.x;     // 128 threads
    float sum = 0.f;
    const float* p = scratch + s * D_DIM + d;
#pragma unroll 4
    for (int blk = 0; blk < 256; blk++) sum += p[(size_t)blk * (B_SZ * D_DIM)];
    a[d] = sum;
    __syncthreads();
    float o = (float)count[s] * b2[d];
    const float4* w = (const float4*)(W2 + d * D_DIM);
#pragma unroll
    for (int k = 0; k < 32; k++) {
        float4 wv = w[k];
        o += a[4 * k + 0] * wv.x + a[4 * k + 1] * wv.y
           + a[4 * k + 2] * wv.z + a[4 * k + 3] * wv.w;
    }
    out[s * D_DIM + d] = o;
}

extern "C" void kernel_launch(void* const* d_in, const int* in_sizes, int n_in,
                              void* d_out, int out_size, void* d_ws, size_t ws_size,
                              hipStream_t stream) {
    const float* embs = (const float*)d_in[0];
    const float* W1   = (const float*)d_in[1];
    const float* b1   = (const float*)d_in[2];
    const float* W2   = (const float*)d_in[3];
    const float* b2   = (const float*)d_in[4];
    const int*   bidx = (const int*)d_in[5];

    char* ws = (char*)d_ws;
    unsigned* w1bf_u  = (unsigned*)(ws + WS_W1BF);
    short*    w1bf    = (short*)(ws + WS_W1BF);
    int*      count   = (int*)(ws + WS_CNT);
    float*    scratch = (float*)(ws + WS_SCRATCH);

    hipMemsetAsync(count, 0, 256 * sizeof(int), stream);
    k_prep_w1<<<64, 256, 0, stream>>>(W1, w1bf_u);
    k_hist<<<512, 256, 0, stream>>>(bidx, count);
    k_main<<<256, 1024, 0, stream>>>(embs, W1, b1, w1bf, bidx, scratch);
    k_out<<<256, 128, 0, stream>>>(scratch, W2, b2, count, (float*)d_out);
}